// Round 1
// baseline (279.121 us; speedup 1.0000x reference)
//
#include <hip/hip_runtime.h>
#include <math.h>

#define NN 8
#define CC 64
#define HH 256
#define WW 256
#define GG 8
#define K2 9
#define OC 72          // G*k2
#define BN_EPS 1e-5f

// ---------------- Kernel 1: adaptive avg pool (N,C,H,W) -> pooled[N*C] ----------
__global__ __launch_bounds__(256) void pool_kernel(const float* __restrict__ x,
                                                   float* __restrict__ pooled) {
    int nc = blockIdx.x;                       // 0 .. N*C-1
    const float4* p4 = (const float4*)(x + (size_t)nc * (HH * WW));
    float s = 0.f;
    for (int i = threadIdx.x; i < (HH * WW) / 4; i += 256) {
        float4 v = p4[i];
        s += (v.x + v.y) + (v.z + v.w);
    }
    // wave reduce (64 lanes)
    for (int off = 32; off > 0; off >>= 1) s += __shfl_down(s, off, 64);
    __shared__ float smem[4];
    int lane = threadIdx.x & 63, wid = threadIdx.x >> 6;
    if (lane == 0) smem[wid] = s;
    __syncthreads();
    if (threadIdx.x == 0) {
        float t = (smem[0] + smem[1]) + (smem[2] + smem[3]);
        pooled[nc] = t * (1.0f / (HH * WW));
    }
}

// ---------------- Kernel 2: 1x1 conv + BN + tanh -> lf[N*72] --------------------
__global__ __launch_bounds__(256) void lf_kernel(const float* __restrict__ pooled,
                                                 const float* __restrict__ conv_w,
                                                 const float* __restrict__ gamma,
                                                 const float* __restrict__ beta,
                                                 const float* __restrict__ mean,
                                                 const float* __restrict__ var,
                                                 float* __restrict__ lf) {
    int j = blockIdx.x * blockDim.x + threadIdx.x;
    if (j >= NN * OC) return;
    int n = j / OC, oc = j % OC;
    const float* pw = conv_w + oc * CC;
    const float* pp = pooled + n * CC;
    float acc = 0.f;
#pragma unroll 8
    for (int c = 0; c < CC; ++c) acc += pp[c] * pw[c];
    float inv = gamma[oc] / sqrtf(var[oc] + BN_EPS);
    lf[j] = tanhf((acc - mean[oc]) * inv + beta[oc]);
}

// ---------------- Kernel 3: dynamic 3x3 depthwise conv + affine combine ---------
// One wave per row: 64 lanes x 4 px = 256 = W. 64 blocks of 4 rows per (n,c).
__global__ __launch_bounds__(256) void main_kernel(const float* __restrict__ x,
                                                   const float* __restrict__ lf,
                                                   const float* __restrict__ pooled,
                                                   const float* __restrict__ lamb_l,
                                                   const float* __restrict__ lamb_h,
                                                   const float* __restrict__ ia,
                                                   float* __restrict__ out) {
    const int wid  = threadIdx.x >> 6;         // wave id 0..3 -> row within block
    const int lane = threadIdx.x & 63;
    const int nc     = blockIdx.x >> 6;        // 64 blocks per (n,c) image
    const int h      = ((blockIdx.x & 63) << 2) + wid;
    const int c      = nc & (CC - 1);
    const int n      = nc >> 6;                // log2(CC)=6
    const int g      = c >> 3;                 // C/G = 8 channels per group

    // wave-uniform weights & per-channel constants (scalar loads)
    const float* lw = lf + (n * OC + g * K2);
    const float w00 = lw[0], w01 = lw[1], w02 = lw[2];
    const float w10 = lw[3], w11 = lw[4], w12 = lw[5];
    const float w20 = lw[6], w21 = lw[7], w22 = lw[8];
    const float ll    = lamb_l[c];
    const float lh1   = lamb_h[c] + 1.0f;
    const float iav   = ia[c];
    const float scale = iav + 1.0f;
    const float bias  = -iav * pooled[nc];

    const float* base = x + (size_t)nc * (HH * WW);
    const int hm = (h == 0) ? 1 : h - 1;             // reflect
    const int hp = (h == HH - 1) ? HH - 2 : h + 1;   // reflect
    const float4 vt = ((const float4*)(base + hm * WW))[lane];
    const float4 vm = ((const float4*)(base + (size_t)h * WW))[lane];
    const float4 vb = ((const float4*)(base + hp * WW))[lane];

    // halo via cross-lane shuffle; reflection at the row ends lives inside our own float4
    float lt = __shfl_up(vt.w, 1, 64);   if (lane == 0)  lt = vt.y;
    float lm = __shfl_up(vm.w, 1, 64);   if (lane == 0)  lm = vm.y;
    float lb = __shfl_up(vb.w, 1, 64);   if (lane == 0)  lb = vb.y;
    float rt = __shfl_down(vt.x, 1, 64); if (lane == 63) rt = vt.z;
    float rm = __shfl_down(vm.x, 1, 64); if (lane == 63) rm = vm.z;
    float rb = __shfl_down(vb.x, 1, 64); if (lane == 63) rb = vb.z;

    const float t[6] = {lt, vt.x, vt.y, vt.z, vt.w, rt};
    const float m[6] = {lm, vm.x, vm.y, vm.z, vm.w, rm};
    const float b[6] = {lb, vb.x, vb.y, vb.z, vb.w, rb};

    float4 o;
    float* op = &o.x;
#pragma unroll
    for (int k = 0; k < 4; ++k) {
        float acc = w00 * t[k] + w01 * t[k + 1] + w02 * t[k + 2]
                  + w10 * m[k] + w11 * m[k + 1] + w12 * m[k + 2]
                  + w20 * b[k] + w21 * b[k + 1] + w22 * b[k + 2];
        op[k] = ll * (scale * acc + bias) + lh1 * m[k + 1];
    }
    ((float4*)(out + (size_t)nc * (HH * WW) + (size_t)h * WW))[lane] = o;
}

extern "C" void kernel_launch(void* const* d_in, const int* in_sizes, int n_in,
                              void* d_out, int out_size, void* d_ws, size_t ws_size,
                              hipStream_t stream) {
    const float* x      = (const float*)d_in[0];
    const float* conv_w = (const float*)d_in[1];
    const float* gamma  = (const float*)d_in[2];
    const float* beta   = (const float*)d_in[3];
    const float* mean   = (const float*)d_in[4];
    const float* var    = (const float*)d_in[5];
    const float* lamb_l = (const float*)d_in[6];
    const float* lamb_h = (const float*)d_in[7];
    const float* ia     = (const float*)d_in[8];
    float* out = (float*)d_out;

    float* pooled = (float*)d_ws;              // N*C = 512 floats
    float* lf     = pooled + NN * CC;          // N*72 = 576 floats

    pool_kernel<<<NN * CC, 256, 0, stream>>>(x, pooled);
    lf_kernel<<<(NN * OC + 255) / 256, 256, 0, stream>>>(pooled, conv_w, gamma, beta,
                                                         mean, var, lf);
    main_kernel<<<NN * CC * (HH / 4), 256, 0, stream>>>(x, lf, pooled, lamb_l, lamb_h,
                                                        ia, out);
}

// Round 2
// 266.468 us; speedup vs baseline: 1.0475x; 1.0475x over previous
//
#include <hip/hip_runtime.h>
#include <math.h>

#define NN 8
#define CC 64
#define HH 256
#define WW 256
#define GG 8
#define K2 9
#define OC 72          // G*k2
#define BN_EPS 1e-5f

// ---------------- Kernel 1: adaptive avg pool (N,C,H,W) -> pooled[N*C] ----------
// 1024 threads/block -> 16 waves; 512 blocks -> 2 blocks/CU = 32 waves/CU (full occ).
__global__ __launch_bounds__(1024) void pool_kernel(const float* __restrict__ x,
                                                    float* __restrict__ pooled) {
    int nc = blockIdx.x;                       // 0 .. N*C-1
    const float4* p4 = (const float4*)(x + (size_t)nc * (HH * WW));
    float s = 0.f;
#pragma unroll 4
    for (int i = threadIdx.x; i < (HH * WW) / 4; i += 1024) {
        float4 v = p4[i];
        s += (v.x + v.y) + (v.z + v.w);
    }
    for (int off = 32; off > 0; off >>= 1) s += __shfl_down(s, off, 64);
    __shared__ float smem[16];
    int lane = threadIdx.x & 63, wid = threadIdx.x >> 6;
    if (lane == 0) smem[wid] = s;
    __syncthreads();
    if (threadIdx.x < 16) {
        float t = smem[threadIdx.x];
        for (int off = 8; off > 0; off >>= 1) t += __shfl_down(t, off, 64);
        if (threadIdx.x == 0) pooled[nc] = t * (1.0f / (HH * WW));
    }
}

// ---------------- Kernel 2: 1x1 conv + BN + tanh -> lf[N*72] --------------------
__global__ __launch_bounds__(256) void lf_kernel(const float* __restrict__ pooled,
                                                 const float* __restrict__ conv_w,
                                                 const float* __restrict__ gamma,
                                                 const float* __restrict__ beta,
                                                 const float* __restrict__ mean,
                                                 const float* __restrict__ var,
                                                 float* __restrict__ lf) {
    int j = blockIdx.x * blockDim.x + threadIdx.x;
    if (j >= NN * OC) return;
    int n = j / OC, oc = j % OC;
    const float* pw = conv_w + oc * CC;
    const float* pp = pooled + n * CC;
    float acc = 0.f;
#pragma unroll 8
    for (int c = 0; c < CC; ++c) acc += pp[c] * pw[c];
    float inv = gamma[oc] / sqrtf(var[oc] + BN_EPS);
    lf[j] = tanhf((acc - mean[oc]) * inv + beta[oc]);
}

// ---------------- Kernel 3: dynamic 3x3 depthwise conv + affine combine ---------
// One wave handles 4 consecutive rows: loads 6 rows (float4/lane), computes 4.
// Block = 4 waves = 16 rows. 16 blocks per (n,c) image. Grid = N*C*16 = 8192.
__global__ __launch_bounds__(256) void main_kernel(const float* __restrict__ x,
                                                   const float* __restrict__ lf,
                                                   const float* __restrict__ pooled,
                                                   const float* __restrict__ lamb_l,
                                                   const float* __restrict__ lamb_h,
                                                   const float* __restrict__ ia,
                                                   float* __restrict__ out) {
    const int wid  = threadIdx.x >> 6;          // wave 0..3
    const int lane = threadIdx.x & 63;
    const int nc   = blockIdx.x >> 4;           // 16 blocks per image
    const int r0   = ((blockIdx.x & 15) << 4) + (wid << 2);  // first output row
    const int c    = nc & (CC - 1);
    const int n    = nc >> 6;
    const int g    = c >> 3;                    // C/G = 8

    // wave-uniform weights & per-channel constants (scalar loads)
    const float* lw = lf + (n * OC + g * K2);
    const float w00 = lw[0], w01 = lw[1], w02 = lw[2];
    const float w10 = lw[3], w11 = lw[4], w12 = lw[5];
    const float w20 = lw[6], w21 = lw[7], w22 = lw[8];
    const float ll    = lamb_l[c];
    const float lh1   = lamb_h[c] + 1.0f;
    const float iav   = ia[c];
    const float scale = iav + 1.0f;
    const float bias  = -iav * pooled[nc];

    const float* base = x + (size_t)nc * (HH * WW);

    float4 v[6];
    float  L[6], R[6];
#pragma unroll
    for (int i = 0; i < 6; ++i) {
        int r = r0 - 1 + i;
        r = (r < 0) ? 1 : ((r > HH - 1) ? HH - 2 : r);   // reflection pad
        v[i] = ((const float4*)(base + r * WW))[lane];
    }
#pragma unroll
    for (int i = 0; i < 6; ++i) {
        L[i] = __shfl_up(v[i].w, 1, 64);   if (lane == 0)  L[i] = v[i].y;
        R[i] = __shfl_down(v[i].x, 1, 64); if (lane == 63) R[i] = v[i].z;
    }

    float* outbase = out + (size_t)nc * (HH * WW);
#pragma unroll
    for (int j = 0; j < 4; ++j) {
        const float t[6] = {L[j],   v[j].x,   v[j].y,   v[j].z,   v[j].w,   R[j]};
        const float m[6] = {L[j+1], v[j+1].x, v[j+1].y, v[j+1].z, v[j+1].w, R[j+1]};
        const float b[6] = {L[j+2], v[j+2].x, v[j+2].y, v[j+2].z, v[j+2].w, R[j+2]};
        float4 o;
        float* op = &o.x;
#pragma unroll
        for (int k = 0; k < 4; ++k) {
            float acc = w00 * t[k] + w01 * t[k + 1] + w02 * t[k + 2]
                      + w10 * m[k] + w11 * m[k + 1] + w12 * m[k + 2]
                      + w20 * b[k] + w21 * b[k + 1] + w22 * b[k + 2];
            op[k] = ll * (scale * acc + bias) + lh1 * m[k + 1];
        }
        ((float4*)(outbase + (size_t)(r0 + j) * WW))[lane] = o;
    }
}

extern "C" void kernel_launch(void* const* d_in, const int* in_sizes, int n_in,
                              void* d_out, int out_size, void* d_ws, size_t ws_size,
                              hipStream_t stream) {
    const float* x      = (const float*)d_in[0];
    const float* conv_w = (const float*)d_in[1];
    const float* gamma  = (const float*)d_in[2];
    const float* beta   = (const float*)d_in[3];
    const float* mean   = (const float*)d_in[4];
    const float* var    = (const float*)d_in[5];
    const float* lamb_l = (const float*)d_in[6];
    const float* lamb_h = (const float*)d_in[7];
    const float* ia     = (const float*)d_in[8];
    float* out = (float*)d_out;

    float* pooled = (float*)d_ws;              // N*C = 512 floats
    float* lf     = pooled + NN * CC;          // N*72 = 576 floats

    pool_kernel<<<NN * CC, 1024, 0, stream>>>(x, pooled);
    lf_kernel<<<(NN * OC + 255) / 256, 256, 0, stream>>>(pooled, conv_w, gamma, beta,
                                                         mean, var, lf);
    main_kernel<<<NN * CC * (HH / 16), 256, 0, stream>>>(x, lf, pooled, lamb_l, lamb_h,
                                                         ia, out);
}